// Round 4
// baseline (443.138 us; speedup 1.0000x reference)
//
#include <hip/hip_runtime.h>
#include <math.h>

#define BATCH 128
#define NINS  4096
#define NHID  128
#define KH    64
#define NPART 64                    // 64 tiles of 64 n per batch
#define PART_STRIDE 136             // [0]=m, [1]=L, [8..135]=o[128]; 16B-aligned
#define O_OFF 8
#define TILES_PER_WAVE 4

typedef __attribute__((ext_vector_type(8))) short short8;   // 8 x bf16
typedef __attribute__((ext_vector_type(4))) float f32x4;

__device__ inline unsigned short f2bf(float f) {
    union { float f; unsigned u; } v; v.f = f;
    return (unsigned short)((v.u + 0x7FFFu + ((v.u >> 16) & 1u)) >> 16);
}

// packed fp32x2 -> bf16x2 (hardware v_cvt_pk_bf16_f32 on gfx950)
__device__ inline void cvt2(short8& f, int j, float a, float b) {
#if __has_builtin(__builtin_amdgcn_cvt_pk_bf16_f32)
    typedef __attribute__((ext_vector_type(2))) __bf16 bf16x2;
    bf16x2 p = __builtin_amdgcn_cvt_pk_bf16_f32(a, b);
    short s[2];
    __builtin_memcpy(s, &p, 4);
    f[j] = s[0]; f[j + 1] = s[1];
#else
    f[j] = (short)f2bf(a); f[j + 1] = (short)f2bf(b);
#endif
}

// --------------------------------------------------------------------------
// Kernel A: c[b][k] = b1[k] + sum_d inputs[b,index,d] * W1[d][k]  (fp32 exact)
// --------------------------------------------------------------------------
__global__ void precompute_c(const float* __restrict__ inputs,
                             const int* __restrict__ index_p,
                             const float* __restrict__ W1,
                             const float* __restrict__ b1,
                             float* __restrict__ c) {
    const int b = blockIdx.x;
    const int k = threadIdx.x;   // 0..63
    const int idx = index_p[0];
    const float* own = inputs + ((size_t)b * NINS + idx) * NHID;
    float acc = b1[k];
    #pragma unroll 8
    for (int d = 0; d < NHID; ++d)
        acc = fmaf(own[d], W1[d * KH + k], acc);
    c[b * KH + k] = acc;
}

// --------------------------------------------------------------------------
// Kernel B: MFMA main pass. 4 waves/block, 4 tiles/wave, tile = 64n x 64k.
// h = x(bf16) @ Wb(bf16) + c  via 16x16x32 bf16 MFMA (fp32 accumulate).
// A-frags loaded straight from global (A[m=lane&15][k=quad*8+j]) with
// hardware packed fp32->bf16; all 16 B-frags of Wb resident in regs.
// --------------------------------------------------------------------------
__global__ __launch_bounds__(256)
void att_partial(const float* __restrict__ inputs,
                 const float* __restrict__ W1,
                 const float* __restrict__ W2,
                 const float* __restrict__ b2_p,
                 const float* __restrict__ c,
                 float* __restrict__ part) {
    __shared__ float ebuf[4][64];
    const int lane = threadIdx.x & 63;
    const int wv   = threadIdx.x >> 6;
    const int b    = blockIdx.y;
    const int quad = lane >> 4;
    const int m16  = lane & 15;

    const float* Wb = W1 + (size_t)NHID * KH;             // rows d=128..255
    const float* xb = inputs + (size_t)b * NINS * NHID;

    // ---- B fragments (whole Wb), loaded once: Bf[ks][nf] ----
    short8 Bf[4][4];
    #pragma unroll
    for (int ks = 0; ks < 4; ++ks)
        #pragma unroll
        for (int nf = 0; nf < 4; ++nf) {
            const float* wp = Wb + (size_t)(ks * 32 + quad * 8) * KH + nf * 16 + m16;
            short8 f;
            #pragma unroll
            for (int j = 0; j < 8; j += 2)
                cvt2(f, j, wp[(size_t)j * KH], wp[(size_t)(j + 1) * KH]);
            Bf[ks][nf] = f;
        }

    float w2v[4];
    #pragma unroll
    for (int nf = 0; nf < 4; ++nf) w2v[nf] = W2[nf * 16 + m16];
    const float b2v = b2_p[0];
    float cv[4];
    #pragma unroll
    for (int nf = 0; nf < 4; ++nf) cv[nf] = c[b * KH + nf * 16 + m16];

    for (int t = 0; t < TILES_PER_WAVE; ++t) {
        const int tile = (blockIdx.x * 4 + wv) * TILES_PER_WAVE + t;
        const int n0   = tile * 64;

        f32x4 acc[4][4];
        #pragma unroll
        for (int mf = 0; mf < 4; ++mf)
            #pragma unroll
            for (int nf = 0; nf < 4; ++nf) {
                f32x4 z = {cv[nf], cv[nf], cv[nf], cv[nf]};
                acc[mf][nf] = z;
            }

        #pragma unroll
        for (int ks = 0; ks < 4; ++ks) {
            short8 Af[4];
            #pragma unroll
            for (int mf = 0; mf < 4; ++mf) {
                const float* row = xb + (size_t)(n0 + mf * 16 + m16) * NHID
                                      + ks * 32 + quad * 8;
                f32x4 a  = *(const f32x4*)row;
                f32x4 bq = *(const f32x4*)(row + 4);
                short8 f;
                cvt2(f, 0, a.x,  a.y);
                cvt2(f, 2, a.z,  a.w);
                cvt2(f, 4, bq.x, bq.y);
                cvt2(f, 6, bq.z, bq.w);
                Af[mf] = f;
            }
            #pragma unroll
            for (int mf = 0; mf < 4; ++mf)
                #pragma unroll
                for (int nf = 0; nf < 4; ++nf)
                    acc[mf][nf] = __builtin_amdgcn_mfma_f32_16x16x32_bf16(
                        Af[mf], Bf[ks][nf], acc[mf][nf], 0, 0, 0);
        }

        // ---- epilogue: att[n] = b2 + sum_k relu(h[n][k]) * W2[k] ----
        // C layout: row(n) = quad*4 + r, col(k) = nf*16 + m16
        float att[4][4];   // [mf][r]
        #pragma unroll
        for (int mf = 0; mf < 4; ++mf)
            #pragma unroll
            for (int r = 0; r < 4; ++r) {
                float s = 0.0f;
                #pragma unroll
                for (int nf = 0; nf < 4; ++nf)
                    s = fmaf(fmaxf(acc[mf][nf][r], 0.0f), w2v[nf], s);
                s += __shfl_xor(s, 1);
                s += __shfl_xor(s, 2);
                s += __shfl_xor(s, 4);
                s += __shfl_xor(s, 8);
                att[mf][r] = s + b2v;
            }

        // wave max / exp / sum  (each lane's 16 att's partition n by quad)
        float mx = att[0][0];
        #pragma unroll
        for (int mf = 0; mf < 4; ++mf)
            #pragma unroll
            for (int r = 0; r < 4; ++r) mx = fmaxf(mx, att[mf][r]);
        mx = fmaxf(mx, __shfl_xor(mx, 16));
        mx = fmaxf(mx, __shfl_xor(mx, 32));

        float ev[4][4];
        float L = 0.0f;
        #pragma unroll
        for (int mf = 0; mf < 4; ++mf)
            #pragma unroll
            for (int r = 0; r < 4; ++r) {
                ev[mf][r] = __expf(att[mf][r] - mx);
                L += ev[mf][r];
            }
        L += __shfl_xor(L, 16);
        L += __shfl_xor(L, 32);

        // stage e[64] in per-wave LDS (one writer lane per quad-group)
        if (m16 == 0) {
            #pragma unroll
            for (int mf = 0; mf < 4; ++mf)
                #pragma unroll
                for (int r = 0; r < 4; ++r)
                    ebuf[wv][mf * 16 + quad * 4 + r] = ev[mf][r];
        }
        // same-wave DS ordering; compiler inserts lgkmcnt wait before reads

        // ---- weighted sum: o[d] = sum_n e_n * x[n][d] ----
        const int G  = lane >> 5;            // n-half
        const int db = (lane & 31) * 4;      // d-base (float4)
        f32x4 o = {0.0f, 0.0f, 0.0f, 0.0f};
        #pragma unroll
        for (int nn = 0; nn < 32; nn += 8) {
            f32x4 e4a = *(const f32x4*)&ebuf[wv][G * 32 + nn];
            f32x4 e4b = *(const f32x4*)&ebuf[wv][G * 32 + nn + 4];
            const float* xrow0 = xb + (size_t)(n0 + G * 32 + nn) * NHID + db;
            #pragma unroll
            for (int j = 0; j < 4; ++j) {
                f32x4 xv = *(const f32x4*)(xrow0 + (size_t)j * NHID);
                o += xv * e4a[j];
            }
            #pragma unroll
            for (int j = 0; j < 4; ++j) {
                f32x4 xv = *(const f32x4*)(xrow0 + (size_t)(j + 4) * NHID);
                o += xv * e4b[j];
            }
        }
        #pragma unroll
        for (int i = 0; i < 4; ++i) o[i] += __shfl_xor(o[i], 32);

        float* p = part + (size_t)(b * NPART + tile) * PART_STRIDE;
        if (lane == 0) { p[0] = mx; p[1] = L; }
        if (lane < 32) *(f32x4*)(p + O_OFF + db) = o;
    }
}

// --------------------------------------------------------------------------
// Kernel C: merge 64 partials per batch -> out[b][d]
// --------------------------------------------------------------------------
__global__ void finalize(const float* __restrict__ part,
                         float* __restrict__ out) {
    const int b = blockIdx.x;
    const int d = threadIdx.x;   // 0..127
    const float* pb = part + (size_t)b * NPART * PART_STRIDE;

    float M = pb[0];
    #pragma unroll 8
    for (int p = 1; p < NPART; ++p)
        M = fmaxf(M, pb[p * PART_STRIDE]);

    float S = 0.0f, acc = 0.0f;
    #pragma unroll 4
    for (int p = 0; p < NPART; ++p) {
        const float sc = __expf(pb[p * PART_STRIDE] - M);
        S   = fmaf(sc, pb[p * PART_STRIDE + 1], S);
        acc = fmaf(sc, pb[p * PART_STRIDE + O_OFF + d], acc);
    }
    out[b * NHID + d] = acc / S;
}

// --------------------------------------------------------------------------
extern "C" void kernel_launch(void* const* d_in, const int* in_sizes, int n_in,
                              void* d_out, int out_size, void* d_ws, size_t ws_size,
                              hipStream_t stream) {
    const float* inputs = (const float*)d_in[0];
    const int*   index  = (const int*)  d_in[1];
    // d_in[2] = claims (unused by forward)
    const float* W1     = (const float*)d_in[3];
    const float* b1     = (const float*)d_in[4];
    const float* W2     = (const float*)d_in[5];
    const float* b2     = (const float*)d_in[6];
    float* out = (float*)d_out;

    float* c    = (float*)d_ws;                 // 128*64 floats = 32 KB
    float* part = c + BATCH * KH;               // 128*64*136 floats ~= 4.25 MB

    precompute_c<<<dim3(BATCH), dim3(64), 0, stream>>>(inputs, index, W1, b1, c);

    dim3 gB(4, BATCH);                          // 512 blocks x 4 waves, 4 tiles/wave
    att_partial<<<gB, dim3(256), 0, stream>>>(inputs, W1, W2, b2, c, part);

    finalize<<<dim3(BATCH), dim3(NHID), 0, stream>>>(part, out);
}

// Round 5
// 417.714 us; speedup vs baseline: 1.0609x; 1.0609x over previous
//
#include <hip/hip_runtime.h>
#include <math.h>

#define BATCH 128
#define NINS  4096
#define NHID  128
#define KH    64
#define NPART 128                   // 128 tiles of 32 n per batch
#define PART_STRIDE 136             // [0]=m, [1]=L, [8..135]=o[128]; 16B-aligned
#define O_OFF 8
#define TPW 2                       // tiles per wave

typedef __attribute__((ext_vector_type(8))) short short8;   // 8 x bf16
typedef __attribute__((ext_vector_type(4))) float f32x4;

__device__ inline unsigned short f2bf(float f) {
    union { float f; unsigned u; } v; v.f = f;
    return (unsigned short)((v.u + 0x7FFFu + ((v.u >> 16) & 1u)) >> 16);
}

// packed fp32x2 -> bf16x2 as u32 (hardware v_cvt_pk_bf16_f32 on gfx950)
__device__ inline unsigned cvt_pk_u32(float a, float b) {
#if __has_builtin(__builtin_amdgcn_cvt_pk_bf16_f32)
    typedef __attribute__((ext_vector_type(2))) __bf16 bf16x2;
    bf16x2 p = __builtin_amdgcn_cvt_pk_bf16_f32(a, b);
    unsigned u; __builtin_memcpy(&u, &p, 4); return u;
#else
    return (unsigned)f2bf(a) | ((unsigned)f2bf(b) << 16);
#endif
}

__device__ inline void cvt2(short8& f, int j, float a, float b) {
    unsigned u = cvt_pk_u32(a, b);
    f[j] = (short)(u & 0xffffu); f[j + 1] = (short)(u >> 16);
}

// --------------------------------------------------------------------------
// Kernel A: c[b][k] = b1[k] + sum_d inputs[b,index,d] * W1[d][k]  (fp32 exact)
// --------------------------------------------------------------------------
__global__ void precompute_c(const float* __restrict__ inputs,
                             const int* __restrict__ index_p,
                             const float* __restrict__ W1,
                             const float* __restrict__ b1,
                             float* __restrict__ c) {
    const int b = blockIdx.x;
    const int k = threadIdx.x;   // 0..63
    const int idx = index_p[0];
    const float* own = inputs + ((size_t)b * NINS + idx) * NHID;
    float acc = b1[k];
    #pragma unroll 8
    for (int d = 0; d < NHID; ++d)
        acc = fmaf(own[d], W1[d * KH + k], acc);
    c[b * KH + k] = acc;
}

// --------------------------------------------------------------------------
// Kernel B: MFMA main pass, occupancy-tuned. 4 waves/block, 2 tiles/wave,
// tile = 32n x 64hidden, K=128. Wb staged in LDS as bf16 [n][k] (padded);
// B-frags via ds_read_b128; A-frags straight from global + packed cvt.
// acc 32 + Bf 16 + Af 8 VGPRs -> target 4 waves/SIMD.
// --------------------------------------------------------------------------
__global__ __launch_bounds__(256, 4)
void att_partial(const float* __restrict__ inputs,
                 const float* __restrict__ W1,
                 const float* __restrict__ W2,
                 const float* __restrict__ b2_p,
                 const float* __restrict__ c,
                 float* __restrict__ part) {
    __shared__ unsigned short WbT[KH][NHID + 8];   // [hidden n][k], pad 8 bf16
    __shared__ float ebuf[4][32];

    const int tid  = threadIdx.x;
    const int lane = tid & 63;
    const int wv   = tid >> 6;
    const int b    = blockIdx.y;
    const int quad = lane >> 4;
    const int m16  = lane & 15;

    const float* xb = inputs + (size_t)b * NINS * NHID;

    // ---- stage WbT[n][k] = bf16(W1[128+k][n]) ----
    {
        const int n  = tid >> 2;            // 0..63
        const int kb = (tid & 3) * 32;      // 0,32,64,96
        const float* wp = W1 + (size_t)(NHID + kb) * KH + n;
        #pragma unroll
        for (int j = 0; j < 32; j += 2) {
            unsigned u = cvt_pk_u32(wp[(size_t)j * KH], wp[(size_t)(j + 1) * KH]);
            *(unsigned*)&WbT[n][kb + j] = u;
        }
    }
    __syncthreads();

    float w2v[4];
    #pragma unroll
    for (int nf = 0; nf < 4; ++nf) w2v[nf] = W2[nf * 16 + m16];
    const float b2v = b2_p[0];
    float cv[4];
    #pragma unroll
    for (int nf = 0; nf < 4; ++nf) cv[nf] = c[b * KH + nf * 16 + m16];

    for (int t = 0; t < TPW; ++t) {
        const int tile = (blockIdx.x * 4 + wv) * TPW + t;   // 0..127
        const int n0   = tile * 32;

        f32x4 acc[2][4];
        #pragma unroll
        for (int mf = 0; mf < 2; ++mf)
            #pragma unroll
            for (int nf = 0; nf < 4; ++nf) {
                f32x4 z = {cv[nf], cv[nf], cv[nf], cv[nf]};
                acc[mf][nf] = z;
            }

        #pragma unroll
        for (int ks = 0; ks < 4; ++ks) {
            short8 Bf[4];
            #pragma unroll
            for (int nf = 0; nf < 4; ++nf)
                Bf[nf] = *(const short8*)&WbT[nf * 16 + m16][ks * 32 + quad * 8];

            short8 Af[2];
            #pragma unroll
            for (int mf = 0; mf < 2; ++mf) {
                const float* row = xb + (size_t)(n0 + mf * 16 + m16) * NHID
                                      + ks * 32 + quad * 8;
                f32x4 a  = *(const f32x4*)row;
                f32x4 bq = *(const f32x4*)(row + 4);
                short8 f;
                cvt2(f, 0, a.x,  a.y);
                cvt2(f, 2, a.z,  a.w);
                cvt2(f, 4, bq.x, bq.y);
                cvt2(f, 6, bq.z, bq.w);
                Af[mf] = f;
            }
            #pragma unroll
            for (int mf = 0; mf < 2; ++mf)
                #pragma unroll
                for (int nf = 0; nf < 4; ++nf)
                    acc[mf][nf] = __builtin_amdgcn_mfma_f32_16x16x32_bf16(
                        Af[mf], Bf[nf], acc[mf][nf], 0, 0, 0);
        }

        // ---- epilogue: att[n] = b2 + sum_k relu(h[n][k]) * W2[k] ----
        // C layout: row(n-in-tile) = mf*16 + quad*4 + r, col(hidden) = nf*16+m16
        float att[2][4];
        #pragma unroll
        for (int mf = 0; mf < 2; ++mf)
            #pragma unroll
            for (int r = 0; r < 4; ++r) {
                float s = 0.0f;
                #pragma unroll
                for (int nf = 0; nf < 4; ++nf)
                    s = fmaf(fmaxf(acc[mf][nf][r], 0.0f), w2v[nf], s);
                s += __shfl_xor(s, 1);
                s += __shfl_xor(s, 2);
                s += __shfl_xor(s, 4);
                s += __shfl_xor(s, 8);
                att[mf][r] = s + b2v;
            }

        float mx = att[0][0];
        #pragma unroll
        for (int mf = 0; mf < 2; ++mf)
            #pragma unroll
            for (int r = 0; r < 4; ++r) mx = fmaxf(mx, att[mf][r]);
        mx = fmaxf(mx, __shfl_xor(mx, 16));
        mx = fmaxf(mx, __shfl_xor(mx, 32));

        float ev[2][4];
        float L = 0.0f;
        #pragma unroll
        for (int mf = 0; mf < 2; ++mf)
            #pragma unroll
            for (int r = 0; r < 4; ++r) {
                ev[mf][r] = __expf(att[mf][r] - mx);
                L += ev[mf][r];
            }
        L += __shfl_xor(L, 16);
        L += __shfl_xor(L, 32);

        if (m16 == 0) {
            #pragma unroll
            for (int mf = 0; mf < 2; ++mf)
                #pragma unroll
                for (int r = 0; r < 4; ++r)
                    ebuf[wv][mf * 16 + quad * 4 + r] = ev[mf][r];
        }
        // same-wave DS ordering; compiler inserts lgkmcnt wait before reads

        // ---- weighted sum: o[d] = sum_n e_n * x[n][d], n in 32-tile ----
        const int G  = lane >> 5;            // n-half (16 each)
        const int db = (lane & 31) * 4;      // d-base (float4)
        f32x4 e4[4];
        #pragma unroll
        for (int i = 0; i < 4; ++i)
            e4[i] = *(const f32x4*)&ebuf[wv][G * 16 + i * 4];

        f32x4 o = {0.0f, 0.0f, 0.0f, 0.0f};
        const float* xr = xb + (size_t)(n0 + G * 16) * NHID + db;
        #pragma unroll
        for (int jj = 0; jj < 16; ++jj) {
            f32x4 xv = *(const f32x4*)(xr + (size_t)jj * NHID);
            o += xv * e4[jj >> 2][jj & 3];
        }
        #pragma unroll
        for (int i = 0; i < 4; ++i) o[i] += __shfl_xor(o[i], 32);

        float* p = part + (size_t)(b * NPART + tile) * PART_STRIDE;
        if (lane == 0) { p[0] = mx; p[1] = L; }
        if (lane < 32) *(f32x4*)(p + O_OFF + db) = o;
    }
}

// --------------------------------------------------------------------------
// Kernel C: merge 128 partials per batch -> out[b][d]
// --------------------------------------------------------------------------
__global__ void finalize(const float* __restrict__ part,
                         float* __restrict__ out) {
    const int b = blockIdx.x;
    const int d = threadIdx.x;   // 0..127
    const float* pb = part + (size_t)b * NPART * PART_STRIDE;

    float M = pb[0];
    #pragma unroll 8
    for (int p = 1; p < NPART; ++p)
        M = fmaxf(M, pb[p * PART_STRIDE]);

    float S = 0.0f, acc = 0.0f;
    #pragma unroll 4
    for (int p = 0; p < NPART; ++p) {
        const float sc = __expf(pb[p * PART_STRIDE] - M);
        S   = fmaf(sc, pb[p * PART_STRIDE + 1], S);
        acc = fmaf(sc, pb[p * PART_STRIDE + O_OFF + d], acc);
    }
    out[b * NHID + d] = acc / S;
}

// --------------------------------------------------------------------------
extern "C" void kernel_launch(void* const* d_in, const int* in_sizes, int n_in,
                              void* d_out, int out_size, void* d_ws, size_t ws_size,
                              hipStream_t stream) {
    const float* inputs = (const float*)d_in[0];
    const int*   index  = (const int*)  d_in[1];
    // d_in[2] = claims (unused by forward)
    const float* W1     = (const float*)d_in[3];
    const float* b1     = (const float*)d_in[4];
    const float* W2     = (const float*)d_in[5];
    const float* b2     = (const float*)d_in[6];
    float* out = (float*)d_out;

    float* c    = (float*)d_ws;                 // 128*64 floats = 32 KB
    float* part = c + BATCH * KH;               // 128*128*136 floats ~= 8.9 MB

    precompute_c<<<dim3(BATCH), dim3(64), 0, stream>>>(inputs, index, W1, b1, c);

    dim3 gB(NPART / (4 * TPW), BATCH);          // 16 x 128 = 2048 blocks, 4 waves
    att_partial<<<gB, dim3(256), 0, stream>>>(inputs, W1, W2, b2, c, part);

    finalize<<<dim3(BATCH), dim3(NHID), 0, stream>>>(part, out);
}

// Round 6
// 413.096 us; speedup vs baseline: 1.0727x; 1.0112x over previous
//
#include <hip/hip_runtime.h>
#include <math.h>

#define BATCH 128
#define NINS  4096
#define NHID  128
#define KH    64
#define NPART 128                   // 128 tiles of 32 n per batch
#define PART_STRIDE 136             // [0]=m, [1]=L, [8..135]=o[128]; 16B-aligned
#define O_OFF 8
#define TPW 2                       // tiles per wave
#define XP 136                      // X/WbT row pitch in ushort (128 bf16 + 8 pad)

typedef __attribute__((ext_vector_type(8))) short short8;   // 8 x bf16
typedef __attribute__((ext_vector_type(4))) float f32x4;

__device__ inline unsigned short f2bf(float f) {
    union { float f; unsigned u; } v; v.f = f;
    return (unsigned short)((v.u + 0x7FFFu + ((v.u >> 16) & 1u)) >> 16);
}

// packed fp32x2 -> bf16x2 as u32 (hardware v_cvt_pk_bf16_f32 on gfx950)
__device__ inline unsigned cvt_pk_u32(float a, float b) {
#if __has_builtin(__builtin_amdgcn_cvt_pk_bf16_f32)
    typedef __attribute__((ext_vector_type(2))) __bf16 bf16x2;
    bf16x2 p = __builtin_amdgcn_cvt_pk_bf16_f32(a, b);
    unsigned u; __builtin_memcpy(&u, &p, 4); return u;
#else
    return (unsigned)f2bf(a) | ((unsigned)f2bf(b) << 16);
#endif
}

// --------------------------------------------------------------------------
// Kernel A: c[b][k] = b1[k] + sum_d inputs[b,index,d] * W1[d][k]  (fp32 exact)
// --------------------------------------------------------------------------
__global__ void precompute_c(const float* __restrict__ inputs,
                             const int* __restrict__ index_p,
                             const float* __restrict__ W1,
                             const float* __restrict__ b1,
                             float* __restrict__ c) {
    const int b = blockIdx.x;
    const int k = threadIdx.x;   // 0..63
    const int idx = index_p[0];
    const float* own = inputs + ((size_t)b * NINS + idx) * NHID;
    float acc = b1[k];
    #pragma unroll 8
    for (int d = 0; d < NHID; ++d)
        acc = fmaf(own[d], W1[d * KH + k], acc);
    c[b * KH + k] = acc;
}

// --------------------------------------------------------------------------
// Kernel B: MFMA main pass, LDS-transposed staging.
// 4 waves/block, 2 tiles/wave, tile = 32n x 64hidden, K=128.
// Global reads are lane-contiguous float4 streams (1KB/instr); the
// n-major -> fragment transpose happens through a per-wave LDS tile
// (bf16, pitch 136 ushort: A-frag ds_read_b128 at the structural
// 8-lane/bank-group baseline). Software-pipelined: A-frags of tile t
// hoisted to regs, then tile t+1 staged while MFMA/epilogue/WS of t run.
// --------------------------------------------------------------------------
__global__ __launch_bounds__(256, 3)
void att_partial(const float* __restrict__ inputs,
                 const float* __restrict__ W1,
                 const float* __restrict__ W2,
                 const float* __restrict__ b2_p,
                 const float* __restrict__ c,
                 float* __restrict__ part) {
    __shared__ unsigned short WbT[KH][XP];       // [hidden n][k] bf16, 17.4 KB
    __shared__ unsigned short Xs[4][32][XP];     // per-wave x tile bf16, 34.8 KB
    __shared__ float ebuf[4][32];

    const int tid  = threadIdx.x;
    const int lane = tid & 63;
    const int wv   = tid >> 6;
    const int b    = blockIdx.y;
    const int quad = lane >> 4;
    const int m16  = lane & 15;

    const float* xb = inputs + (size_t)b * NINS * NHID;

    // ---- stage WbT[n][k] = bf16(W1[128+k][n]) (whole block, once) ----
    {
        const int n  = tid >> 2;            // 0..63
        const int kb = (tid & 3) * 32;      // 0,32,64,96
        const float* wp = W1 + (size_t)(NHID + kb) * KH + n;
        #pragma unroll
        for (int j = 0; j < 32; j += 2) {
            unsigned u = cvt_pk_u32(wp[(size_t)j * KH], wp[(size_t)(j + 1) * KH]);
            *(unsigned*)&WbT[n][kb + j] = u;
        }
    }
    __syncthreads();

    float w2v[4];
    #pragma unroll
    for (int nf = 0; nf < 4; ++nf) w2v[nf] = W2[nf * 16 + m16];
    const float b2v = b2_p[0];
    float cv[4];
    #pragma unroll
    for (int nf = 0; nf < 4; ++nf) cv[nf] = c[b * KH + nf * 16 + m16];

    const int base = (blockIdx.x * 4 + wv) * TPW;   // first tile of this wave

    // ---- stage one 32-row x tile into this wave's LDS slice ----
    auto stage = [&](int n0) {
        const float* src = xb + (size_t)n0 * NHID;
        unsigned short* xw = &Xs[wv][0][0];
        #pragma unroll
        for (int i = 0; i < 16; ++i) {
            const int f = i * 64 + lane;            // flat float4 index
            f32x4 v = *(const f32x4*)(src + (size_t)f * 4);   // coalesced stream
            uint2 u;
            u.x = cvt_pk_u32(v.x, v.y);
            u.y = cvt_pk_u32(v.z, v.w);
            *(uint2*)(xw + (f >> 5) * XP + (f & 31) * 4) = u;
        }
    };

    stage(base * 32);

    for (int t = 0; t < TPW; ++t) {
        const int tile = base + t;
        const int n0   = tile * 32;

        // ---- A-frags of tile t from LDS into regs (frees the buffer) ----
        short8 Af[2][4];    // [mf][ks]
        #pragma unroll
        for (int mf = 0; mf < 2; ++mf)
            #pragma unroll
            for (int ks = 0; ks < 4; ++ks)
                Af[mf][ks] = *(const short8*)&Xs[wv][mf * 16 + m16][ks * 32 + quad * 8];

        // ---- stage tile t+1 (overlaps with MFMA/epilogue/WS below) ----
        if (t + 1 < TPW) stage((tile + 1) * 32);

        f32x4 acc[2][4];
        #pragma unroll
        for (int mf = 0; mf < 2; ++mf)
            #pragma unroll
            for (int nf = 0; nf < 4; ++nf) {
                f32x4 z = {cv[nf], cv[nf], cv[nf], cv[nf]};
                acc[mf][nf] = z;
            }

        #pragma unroll
        for (int ks = 0; ks < 4; ++ks) {
            short8 Bf[4];
            #pragma unroll
            for (int nf = 0; nf < 4; ++nf)
                Bf[nf] = *(const short8*)&WbT[nf * 16 + m16][ks * 32 + quad * 8];
            #pragma unroll
            for (int mf = 0; mf < 2; ++mf)
                #pragma unroll
                for (int nf = 0; nf < 4; ++nf)
                    acc[mf][nf] = __builtin_amdgcn_mfma_f32_16x16x32_bf16(
                        Af[mf][ks], Bf[nf], acc[mf][nf], 0, 0, 0);
        }

        // ---- epilogue: att[n] = b2 + sum_k relu(h[n][k]) * W2[k] ----
        // C layout: row(n-in-tile) = mf*16 + quad*4 + r, col(hidden) = nf*16+m16
        float att[2][4];
        #pragma unroll
        for (int mf = 0; mf < 2; ++mf)
            #pragma unroll
            for (int r = 0; r < 4; ++r) {
                float s = 0.0f;
                #pragma unroll
                for (int nf = 0; nf < 4; ++nf)
                    s = fmaf(fmaxf(acc[mf][nf][r], 0.0f), w2v[nf], s);
                s += __shfl_xor(s, 1);
                s += __shfl_xor(s, 2);
                s += __shfl_xor(s, 4);
                s += __shfl_xor(s, 8);
                att[mf][r] = s + b2v;
            }

        float mx = att[0][0];
        #pragma unroll
        for (int mf = 0; mf < 2; ++mf)
            #pragma unroll
            for (int r = 0; r < 4; ++r) mx = fmaxf(mx, att[mf][r]);
        mx = fmaxf(mx, __shfl_xor(mx, 16));
        mx = fmaxf(mx, __shfl_xor(mx, 32));

        float ev[2][4];
        float L = 0.0f;
        #pragma unroll
        for (int mf = 0; mf < 2; ++mf)
            #pragma unroll
            for (int r = 0; r < 4; ++r) {
                ev[mf][r] = __expf(att[mf][r] - mx);
                L += ev[mf][r];
            }
        L += __shfl_xor(L, 16);
        L += __shfl_xor(L, 32);

        if (m16 == 0) {
            #pragma unroll
            for (int mf = 0; mf < 2; ++mf)
                #pragma unroll
                for (int r = 0; r < 4; ++r)
                    ebuf[wv][mf * 16 + quad * 4 + r] = ev[mf][r];
        }
        // same-wave DS ordering; compiler inserts lgkmcnt wait before reads

        // ---- weighted sum: o[d] = sum_n e_n * x[n][d]  (x fp32, L1-hot) ----
        const int G  = lane >> 5;            // n-half (16 each)
        const int db = (lane & 31) * 4;      // d-base (float4)
        f32x4 e4[4];
        #pragma unroll
        for (int i = 0; i < 4; ++i)
            e4[i] = *(const f32x4*)&ebuf[wv][G * 16 + i * 4];

        f32x4 o = {0.0f, 0.0f, 0.0f, 0.0f};
        const float* xr = xb + (size_t)(n0 + G * 16) * NHID + db;
        #pragma unroll
        for (int jj = 0; jj < 16; ++jj) {
            f32x4 xv = *(const f32x4*)(xr + (size_t)jj * NHID);
            o += xv * e4[jj >> 2][jj & 3];
        }
        #pragma unroll
        for (int i = 0; i < 4; ++i) o[i] += __shfl_xor(o[i], 32);

        float* p = part + (size_t)(b * NPART + tile) * PART_STRIDE;
        if (lane == 0) { p[0] = mx; p[1] = L; }
        if (lane < 32) *(f32x4*)(p + O_OFF + db) = o;
    }
}

// --------------------------------------------------------------------------
// Kernel C: merge 128 partials per batch -> out[b][d]
// --------------------------------------------------------------------------
__global__ void finalize(const float* __restrict__ part,
                         float* __restrict__ out) {
    const int b = blockIdx.x;
    const int d = threadIdx.x;   // 0..127
    const float* pb = part + (size_t)b * NPART * PART_STRIDE;

    float M = pb[0];
    #pragma unroll 8
    for (int p = 1; p < NPART; ++p)
        M = fmaxf(M, pb[p * PART_STRIDE]);

    float S = 0.0f, acc = 0.0f;
    #pragma unroll 4
    for (int p = 0; p < NPART; ++p) {
        const float sc = __expf(pb[p * PART_STRIDE] - M);
        S   = fmaf(sc, pb[p * PART_STRIDE + 1], S);
        acc = fmaf(sc, pb[p * PART_STRIDE + O_OFF + d], acc);
    }
    out[b * NHID + d] = acc / S;
}

// --------------------------------------------------------------------------
extern "C" void kernel_launch(void* const* d_in, const int* in_sizes, int n_in,
                              void* d_out, int out_size, void* d_ws, size_t ws_size,
                              hipStream_t stream) {
    const float* inputs = (const float*)d_in[0];
    const int*   index  = (const int*)  d_in[1];
    // d_in[2] = claims (unused by forward)
    const float* W1     = (const float*)d_in[3];
    const float* b1     = (const float*)d_in[4];
    const float* W2     = (const float*)d_in[5];
    const float* b2     = (const float*)d_in[6];
    float* out = (float*)d_out;

    float* c    = (float*)d_ws;                 // 128*64 floats = 32 KB
    float* part = c + BATCH * KH;               // 128*128*136 floats ~= 8.9 MB

    precompute_c<<<dim3(BATCH), dim3(64), 0, stream>>>(inputs, index, W1, b1, c);

    dim3 gB(NPART / (4 * TPW), BATCH);          // 16 x 128 = 2048 blocks, 4 waves
    att_partial<<<gB, dim3(256), 0, stream>>>(inputs, W1, W2, b2, c, part);

    finalize<<<dim3(BATCH), dim3(NHID), 0, stream>>>(part, out);
}